// Round 4
// baseline (351.961 us; speedup 1.0000x reference)
//
#include <hip/hip_runtime.h>

namespace {
constexpr int Bn = 16, Hn = 512, Wn = 512;
constexpr int HW  = Hn * Wn;        // 262144
constexpr int CHW = 8 * HW;         // 2097152
constexpr int NCOL = Bn * Wn;       // 8192 dice columns
constexpr int ROWS = 8;             // rows per block
constexpr int GX   = Hn / ROWS;     // 64
constexpr int NBLK = GX * Bn;       // 1024 blocks
constexpr int FBLK = 32;            // finisher blocks; 32*32 slots == NBLK

__device__ __forceinline__ float frcp(float x) { return __builtin_amdgcn_rcpf(x); }

// 4-byte-aligned float4 for the dx-shifted (unaligned) neighbor loads
typedef float f4u __attribute__((ext_vector_type(4), aligned(4)));
} // namespace

// n[c](h,w) = sigmoid(c_map[c][h+DY[c]][w+DX[c]]), zero outside image.
// vote[i] = p[i] * n[7-i].  DX = {1,0,-1,1,-1,1,0,-1}, DY = {1,1,1,0,0,-1,-1,-1}.
// 4 px/lane; dx shifts are direct unaligned loads (L1/L2-hot), no shuffles.

__global__ __launch_bounds__(256, 4) void bicon_main(
    const float* __restrict__ c_map,
    const int*   __restrict__ target,
    const int*   __restrict__ con_target,
    float* __restrict__ col_i, float* __restrict__ col_j, float* __restrict__ col_x,
    double* __restrict__ bscal)
{
    const int tid  = threadIdx.x;        // 0..255
    const int lane = tid & 63;
    const int wv   = tid >> 6;           // 0..3
    const int half = wv & 1;             // which 256-col half
    const int rofs = wv >> 1;            // row parity within pair
    const int b    = blockIdx.y;
    const int h0   = blockIdx.x * ROWS;
    const int wq   = half * 256 + lane * 4;   // first of this lane's 4 columns

    const float* cm = c_map      + (size_t)b * CHW;
    const int*   ct = con_target + (size_t)b * CHW;
    const int*   tg = target     + (size_t)b * HW;

    float s_con = 0.f, s_bi = 0.f, s_bce = 0.f, s_dec = 0.f;
    float ci[4] = {0, 0, 0, 0}, cj[4] = {0, 0, 0, 0}, cx[4] = {0, 0, 0, 0};

#pragma unroll 1
    for (int r = 0; r < ROWS / 2; ++r) {
        const int h    = h0 + 2 * r + rofs;
        const int base = h * Wn + wq;

        // ---- con_target: 8 channel bits x 4 px -> one uint (byte per px) ----
        unsigned lo = 0u;
#pragma unroll
        for (int c = 0; c < 8; ++c) {
            const int4 u = *(const int4*)(ct + c * HW + base);
            lo |= ((unsigned)u.x << c)        | ((unsigned)u.y << (8 + c)) |
                  ((unsigned)u.z << (16 + c)) | ((unsigned)u.w << (24 + c));
        }

        float vmax[4], vmin[4];
#pragma unroll
        for (int k = 0; k < 4; ++k) { vmax[k] = 0.f; vmin[k] = 2.f; }

        // center sigmoid of channel c + fused conmap BCE:
        // log(s) = -log d, log(1-s) = -x - log d, d = 1 + e^-x
        auto center = [&](int c, float s[4]) {
            const float4 v = *(const float4*)(cm + c * HW + base);
            const float xs[4] = {v.x, v.y, v.z, v.w};
#pragma unroll
            for (int k = 0; k < 4; ++k) {
                const float e = __expf(-xs[k]);
                const float d = 1.f + e;
                s[k] = frcp(d);
                const float logd = __logf(d);
                s_con += fmaxf(((lo >> (8 * k + c)) & 1u) ? -logd : (-xs[k] - logd),
                               -100.f);
            }
        };
        // neighbor sigmoid of channel c at (h+dy, w+dx); zero outside image
        auto nbr = [&](int c, int dy, int dx, float n[4]) {
            const int hn = h + dy;
            if ((unsigned)hn < (unsigned)Hn) {          // wave-uniform
                const f4u v = *(const f4u*)(cm + c * HW + hn * Wn + (wq + dx));
                const float xs[4] = {v.x, v.y, v.z, v.w};
#pragma unroll
                for (int k = 0; k < 4; ++k) n[k] = frcp(1.f + __expf(-xs[k]));
                if (dx == 1 && wq == Wn - 4) n[3] = 0.f;   // w+1 == 512
                if (dx == -1 && wq == 0)     n[0] = 0.f;   // w-1 == -1
            } else {
#pragma unroll
                for (int k = 0; k < 4; ++k) n[k] = 0.f;
            }
        };
        // vote[i] = p[i] * n[7-i]: max/min + fused bimap BCE
        auto vote = [&](int i, const float si[4], const float nn[4]) {
#pragma unroll
            for (int k = 0; k < 4; ++k) {
                const float v = si[k] * nn[k];
                vmax[k] = fmaxf(vmax[k], v);
                vmin[k] = fminf(vmin[k], v);
                s_bi += fmaxf(__logf(((lo >> (8 * k + i)) & 1u) ? v : 1.f - v),
                              -100.f);
            }
        };

        { // pair (0,7): N0 @ (+1,+1), N7 @ (-1,-1)
            float pa[4], pb[4], na[4], nb_[4];
            center(0, pa); center(7, pb);
            nbr(0, +1, +1, na);  vote(7, pb, na);
            nbr(7, -1, -1, nb_); vote(0, pa, nb_);
        }
        { // pair (1,6): N1 @ (+1,0), N6 @ (-1,0)
            float pa[4], pb[4], na[4], nb_[4];
            center(1, pa); center(6, pb);
            nbr(1, +1, 0, na);   vote(6, pb, na);
            nbr(6, -1, 0, nb_);  vote(1, pa, nb_);
        }
        { // pair (2,5): N2 @ (+1,-1), N5 @ (-1,+1)
            float pa[4], pb[4], na[4], nb_[4];
            center(2, pa); center(5, pb);
            nbr(2, +1, -1, na);  vote(5, pb, na);
            nbr(5, -1, +1, nb_); vote(2, pa, nb_);
        }
        { // pair (3,4): N3 @ (0,+1), N4 @ (0,-1)
            float pa[4], pb[4], na[4], nb_[4];
            center(3, pa); center(4, pb);
            nbr(3, 0, +1, na);   vote(4, pb, na);
            nbr(4, 0, -1, nb_);  vote(3, pa, nb_);
        }

        // ---- per-pixel tail: bce, decouple, dice accumulation ----
        const int4 t = *(const int4*)(tg + base);
        const int tk[4] = {t.x, t.y, t.z, t.w};
#pragma unroll
        for (int k = 0; k < 4; ++k) {
            const float fm = vmax[k];
            s_bce += fmaxf(__logf(tk[k] ? fm : 1.f - fm), -100.f);
            const int sc = __popc((int)((lo >> (8 * k)) & 0xffu));
            s_dec += (sc > 0 && sc < 8) ? fmaxf(__logf(1.f - vmin[k]), -100.f) : 0.f;
            ci[k] += (float)tk[k];
            cj[k] += fm;
            cx[k] += tk[k] ? fm : 0.f;
        }
    }

    // ---- dice partials -> LDS (combine the two row-parity waves per half) ----
    __shared__ float cred[3][4][256];   // 12 KB
#pragma unroll
    for (int k = 0; k < 4; ++k) {
        cred[0][wv][(lane << 2) + k] = ci[k];
        cred[1][wv][(lane << 2) + k] = cj[k];
        cred[2][wv][(lane << 2) + k] = cx[k];
    }

    // ---- scalar sums: wave shuffle reduction ----
#pragma unroll
    for (int off = 32; off > 0; off >>= 1) {
        s_con += __shfl_down(s_con, off);
        s_bi  += __shfl_down(s_bi,  off);
        s_bce += __shfl_down(s_bce, off);
        s_dec += __shfl_down(s_dec, off);
    }
    __shared__ float wred[4][4];
    if (lane == 0) {
        wred[wv][0] = s_con; wred[wv][1] = s_bi;
        wred[wv][2] = s_bce; wred[wv][3] = s_dec;
    }
    __syncthreads();

    // waves {hj, hj+2} hold column half hj
#pragma unroll
    for (int j = tid; j < 512; j += 256) {
        const int hj = j >> 8, cidx = j & 255;
        const float a0 = cred[0][hj][cidx] + cred[0][hj + 2][cidx];
        const float a1 = cred[1][hj][cidx] + cred[1][hj + 2][cidx];
        const float a2 = cred[2][hj][cidx] + cred[2][hj + 2][cidx];
        atomicAdd(&col_i[b * Wn + j], a0);
        atomicAdd(&col_j[b * Wn + j], a1);
        atomicAdd(&col_x[b * Wn + j], a2);
    }
    if (tid < 4) {
        bscal[((size_t)blockIdx.y * GX + blockIdx.x) * 4 + tid] =
            (double)(wred[0][tid] + wred[1][tid] + wred[2][tid] + wred[3][tid]);
    }
}

__global__ __launch_bounds__(256) void bicon_finish(
    const float* __restrict__ col_i,
    const float* __restrict__ col_j,
    const float* __restrict__ col_x,
    const double* __restrict__ bscal,
    float* __restrict__ out)
{
    const int tid = threadIdx.x;
    const int col = blockIdx.x * 256 + tid;      // exactly NCOL threads total

    double part;
    {
        const float fi = col_i[col], fj = col_j[col], fx = col_x[col];
        part = (1.0 - (2.0 * (double)fx + 0.001) /
                      ((double)fi + (double)fj + 0.001)) / 8192.0;
    }
    if (tid < 32) {   // 32 bscal slots per block: 32 blocks * 32 = 1024 = NBLK
        const int s = blockIdx.x * 32 + tid;
        const double c0 = bscal[s * 4 + 0], c1 = bscal[s * 4 + 1];
        const double c2 = bscal[s * 4 + 2], c3 = bscal[s * 4 + 3];
        part += -0.8 * c0 / 33554432.0 - 0.2 * c1 / 33554432.0
                - c2 / 4194304.0 - c3 / 4194304.0;
    }
#pragma unroll
    for (int off = 32; off > 0; off >>= 1) part += __shfl_down(part, off);
    __shared__ double red[4];
    if ((tid & 63) == 0) red[tid >> 6] = part;
    __syncthreads();
    if (tid == 0) atomicAdd(out, (float)(red[0] + red[1] + red[2] + red[3]));
}

extern "C" void kernel_launch(void* const* d_in, const int* in_sizes, int n_in,
                              void* d_out, int out_size, void* d_ws, size_t ws_size,
                              hipStream_t stream) {
    const float* c_map      = (const float*)d_in[0];
    const int*   target     = (const int*)d_in[1];
    const int*   con_target = (const int*)d_in[2];
    float* out = (float*)d_out;

    char* ws = (char*)d_ws;
    float*  col_i = (float*)ws;                               // 8192 floats
    float*  col_j = col_i + NCOL;
    float*  col_x = col_j + NCOL;
    double* bscal = (double*)(ws + 3 * NCOL * sizeof(float)); // 1024*4 doubles

    hipMemsetAsync(d_ws, 0, 3 * NCOL * sizeof(float), stream); // zero col tables
    hipMemsetAsync(d_out, 0, sizeof(float), stream);           // finisher atomics here

    dim3 grid(GX, Bn);       // 64 x 16 = 1024 blocks
    dim3 block(256);
    bicon_main<<<grid, block, 0, stream>>>(c_map, target, con_target,
                                           col_i, col_j, col_x, bscal);
    bicon_finish<<<FBLK, 256, 0, stream>>>(col_i, col_j, col_x, bscal, out);
}

// Round 5
// 318.845 us; speedup vs baseline: 1.1039x; 1.1039x over previous
//
#include <hip/hip_runtime.h>

namespace {
constexpr int Bn = 16, Hn = 512, Wn = 512;
constexpr int HW  = Hn * Wn;        // 262144
constexpr int CHW = 8 * HW;         // 2097152
constexpr int NCOL = Bn * Wn;       // 8192 dice columns
constexpr int ROWS = 8;             // rows per block
constexpr int GX   = Hn / ROWS;     // 64
constexpr int NBLK = GX * Bn;       // 1024 blocks
constexpr int FBLK = 32;            // finisher blocks; 32*32 slots == NBLK

__device__ __forceinline__ float frcp(float x) { return __builtin_amdgcn_rcpf(x); }

// dword-aligned float4 for the dx-shifted (unaligned) neighbor loads
typedef float f4u __attribute__((ext_vector_type(4), aligned(4)));
} // namespace

// n[c](h,w) = sigmoid(c_map[c][h+DY[c]][w+DX[c]]), zero outside image.
// vote[i] = p[i] * n[7-i].  DX = {1,0,-1,1,-1,1,0,-1}, DY = {1,1,1,0,0,-1,-1,-1}.
// 4 px/lane; dx shifts are direct unaligned loads (L1/L2-hot), no shuffles.
// NOTE: no min-waves in launch_bounds — (256,4) made the allocator target 64
// VGPRs and spill ~100 MB to scratch (R3/R4 WRITE_SIZE). Natural allocation
// with the de-hoisted body is the point of this round.

__global__ __launch_bounds__(256) void bicon_main(
    const float* __restrict__ c_map,
    const int*   __restrict__ target,
    const int*   __restrict__ con_target,
    float* __restrict__ col_i, float* __restrict__ col_j, float* __restrict__ col_x,
    double* __restrict__ bscal)
{
    const int tid  = threadIdx.x;        // 0..255
    const int lane = tid & 63;
    const int wv   = tid >> 6;           // 0..3
    const int half = wv & 1;             // which 256-col half
    const int rofs = wv >> 1;            // row parity within pair
    const int b    = blockIdx.y;
    const int h0   = blockIdx.x * ROWS;
    const int wq   = half * 256 + lane * 4;   // first of this lane's 4 columns

    const float* cm = c_map      + (size_t)b * CHW;
    const int*   ct = con_target + (size_t)b * CHW;
    const int*   tg = target     + (size_t)b * HW;

    float s_con = 0.f, s_bi = 0.f, s_bce = 0.f, s_dec = 0.f;
    float ci[4] = {0, 0, 0, 0}, cj[4] = {0, 0, 0, 0}, cx[4] = {0, 0, 0, 0};

#pragma unroll 1
    for (int r = 0; r < ROWS / 2; ++r) {
        const int h    = h0 + 2 * r + rofs;
        const int base = h * Wn + wq;

        float vmax[4], vmin[4];
        int   sc[4];
#pragma unroll
        for (int k = 0; k < 4; ++k) { vmax[k] = 0.f; vmin[k] = 2.f; sc[k] = 0; }

        // center sigmoid of channel c + fused conmap BCE (bit from tb component):
        // log(s) = -log d, log(1-s) = -x - log d, d = 1 + e^-x
        auto center = [&](int c, const int tb[4], float s[4]) {
            const float4 v = *(const float4*)(cm + c * HW + base);
            const float xs[4] = {v.x, v.y, v.z, v.w};
#pragma unroll
            for (int k = 0; k < 4; ++k) {
                const float e = __expf(-xs[k]);
                const float d = 1.f + e;
                s[k] = frcp(d);
                const float logd = __logf(d);
                s_con += fmaxf(tb[k] ? -logd : (-xs[k] - logd), -100.f);
            }
        };
        // neighbor sigmoid of channel c at (h+dy, w+dx); zero outside image
        auto nbr = [&](int c, int dy, int dx, float n[4]) {
            const int hn = h + dy;
            if ((unsigned)hn < (unsigned)Hn) {          // wave-uniform
                const f4u v = *(const f4u*)(cm + c * HW + hn * Wn + (wq + dx));
                const float xs[4] = {v.x, v.y, v.z, v.w};
#pragma unroll
                for (int k = 0; k < 4; ++k) n[k] = frcp(1.f + __expf(-xs[k]));
                if (dx == 1 && wq == Wn - 4) n[3] = 0.f;   // w+1 == 512
                if (dx == -1 && wq == 0)     n[0] = 0.f;   // w-1 == -1
            } else {
#pragma unroll
                for (int k = 0; k < 4; ++k) n[k] = 0.f;
            }
        };
        // vote[i] = p[i] * n[7-i]: max/min + fused bimap BCE (bit from tb)
        auto vote = [&](const int tb[4], const float si[4], const float nn[4]) {
#pragma unroll
            for (int k = 0; k < 4; ++k) {
                const float v = si[k] * nn[k];
                vmax[k] = fmaxf(vmax[k], v);
                vmin[k] = fminf(vmin[k], v);
                s_bi += fmaxf(__logf(tb[k] ? v : 1.f - v), -100.f);
            }
        };
        // one (ca, cb=7-ca) pair: con_target loads live only inside this scope
        auto pairblk = [&](int ca, int cb, int dya, int dxa) {
            const int4 ua = *(const int4*)(ct + ca * HW + base);
            const int4 ub = *(const int4*)(ct + cb * HW + base);
            const int ta[4] = {ua.x, ua.y, ua.z, ua.w};
            const int tb[4] = {ub.x, ub.y, ub.z, ub.w};
#pragma unroll
            for (int k = 0; k < 4; ++k) sc[k] += ta[k] + tb[k];
            float pa[4], pb[4], na[4], nb_[4];
            center(ca, ta, pa); center(cb, tb, pb);
            nbr(ca, dya, dxa, na);   vote(tb, pb, na);   // vote[cb] = p[cb]*n[ca]
            nbr(cb, -dya, -dxa, nb_); vote(ta, pa, nb_); // vote[ca] = p[ca]*n[cb]
        };

        pairblk(0, 7, +1, +1);   // N0 @ (+1,+1), N7 @ (-1,-1)
        pairblk(1, 6, +1,  0);   // N1 @ (+1, 0), N6 @ (-1, 0)
        pairblk(2, 5, +1, -1);   // N2 @ (+1,-1), N5 @ (-1,+1)
        pairblk(3, 4,  0, +1);   // N3 @ ( 0,+1), N4 @ ( 0,-1)

        // ---- per-pixel tail: bce, decouple, dice accumulation ----
        const int4 t = *(const int4*)(tg + base);
        const int tk[4] = {t.x, t.y, t.z, t.w};
#pragma unroll
        for (int k = 0; k < 4; ++k) {
            const float fm = vmax[k];
            s_bce += fmaxf(__logf(tk[k] ? fm : 1.f - fm), -100.f);
            s_dec += (sc[k] > 0 && sc[k] < 8)
                         ? fmaxf(__logf(1.f - vmin[k]), -100.f) : 0.f;
            ci[k] += (float)tk[k];
            cj[k] += fm;
            cx[k] += tk[k] ? fm : 0.f;
        }
    }

    // ---- dice partials -> LDS (combine the two row-parity waves per half) ----
    __shared__ float cred[3][4][256];   // 12 KB
#pragma unroll
    for (int k = 0; k < 4; ++k) {
        cred[0][wv][(lane << 2) + k] = ci[k];
        cred[1][wv][(lane << 2) + k] = cj[k];
        cred[2][wv][(lane << 2) + k] = cx[k];
    }

    // ---- scalar sums: wave shuffle reduction ----
#pragma unroll
    for (int off = 32; off > 0; off >>= 1) {
        s_con += __shfl_down(s_con, off);
        s_bi  += __shfl_down(s_bi,  off);
        s_bce += __shfl_down(s_bce, off);
        s_dec += __shfl_down(s_dec, off);
    }
    __shared__ float wred[4][4];
    if (lane == 0) {
        wred[wv][0] = s_con; wred[wv][1] = s_bi;
        wred[wv][2] = s_bce; wred[wv][3] = s_dec;
    }
    __syncthreads();

    // waves {hj, hj+2} hold column half hj
#pragma unroll
    for (int j = tid; j < 512; j += 256) {
        const int hj = j >> 8, cidx = j & 255;
        const float a0 = cred[0][hj][cidx] + cred[0][hj + 2][cidx];
        const float a1 = cred[1][hj][cidx] + cred[1][hj + 2][cidx];
        const float a2 = cred[2][hj][cidx] + cred[2][hj + 2][cidx];
        atomicAdd(&col_i[b * Wn + j], a0);
        atomicAdd(&col_j[b * Wn + j], a1);
        atomicAdd(&col_x[b * Wn + j], a2);
    }
    if (tid < 4) {
        bscal[((size_t)blockIdx.y * GX + blockIdx.x) * 4 + tid] =
            (double)(wred[0][tid] + wred[1][tid] + wred[2][tid] + wred[3][tid]);
    }
}

__global__ __launch_bounds__(256) void bicon_finish(
    const float* __restrict__ col_i,
    const float* __restrict__ col_j,
    const float* __restrict__ col_x,
    const double* __restrict__ bscal,
    float* __restrict__ out)
{
    const int tid = threadIdx.x;
    const int col = blockIdx.x * 256 + tid;      // exactly NCOL threads total

    double part;
    {
        const float fi = col_i[col], fj = col_j[col], fx = col_x[col];
        part = (1.0 - (2.0 * (double)fx + 0.001) /
                      ((double)fi + (double)fj + 0.001)) / 8192.0;
    }
    if (tid < 32) {   // 32 bscal slots per block: 32 blocks * 32 = 1024 = NBLK
        const int s = blockIdx.x * 32 + tid;
        const double c0 = bscal[s * 4 + 0], c1 = bscal[s * 4 + 1];
        const double c2 = bscal[s * 4 + 2], c3 = bscal[s * 4 + 3];
        part += -0.8 * c0 / 33554432.0 - 0.2 * c1 / 33554432.0
                - c2 / 4194304.0 - c3 / 4194304.0;
    }
#pragma unroll
    for (int off = 32; off > 0; off >>= 1) part += __shfl_down(part, off);
    __shared__ double red[4];
    if ((tid & 63) == 0) red[tid >> 6] = part;
    __syncthreads();
    if (tid == 0) atomicAdd(out, (float)(red[0] + red[1] + red[2] + red[3]));
}

extern "C" void kernel_launch(void* const* d_in, const int* in_sizes, int n_in,
                              void* d_out, int out_size, void* d_ws, size_t ws_size,
                              hipStream_t stream) {
    const float* c_map      = (const float*)d_in[0];
    const int*   target     = (const int*)d_in[1];
    const int*   con_target = (const int*)d_in[2];
    float* out = (float*)d_out;

    char* ws = (char*)d_ws;
    float*  col_i = (float*)ws;                               // 8192 floats
    float*  col_j = col_i + NCOL;
    float*  col_x = col_j + NCOL;
    double* bscal = (double*)(ws + 3 * NCOL * sizeof(float)); // 1024*4 doubles

    hipMemsetAsync(d_ws, 0, 3 * NCOL * sizeof(float), stream); // zero col tables
    hipMemsetAsync(d_out, 0, sizeof(float), stream);           // finisher atomics here

    dim3 grid(GX, Bn);       // 64 x 16 = 1024 blocks
    dim3 block(256);
    bicon_main<<<grid, block, 0, stream>>>(c_map, target, con_target,
                                           col_i, col_j, col_x, bscal);
    bicon_finish<<<FBLK, 256, 0, stream>>>(col_i, col_j, col_x, bscal, out);
}

// Round 6
// 308.102 us; speedup vs baseline: 1.1424x; 1.0349x over previous
//
#include <hip/hip_runtime.h>

namespace {
constexpr int Bn = 16, Hn = 512, Wn = 512;
constexpr int HW  = Hn * Wn;        // 262144
constexpr int CHW = 8 * HW;         // 2097152
constexpr int NCOL = Bn * Wn;       // 8192 dice columns
constexpr int WALK = 4;             // rows walked per wave
constexpr int ROWSB = 2 * WALK;     // 8 rows per block (2 row-groups)
constexpr int GX   = Hn / ROWSB;    // 64
constexpr int NBLK = GX * Bn;       // 1024 blocks
constexpr int FBLK = 32;            // finisher blocks; 32*32 slots == NBLK

__device__ __forceinline__ float frcp(float x) { return __builtin_amdgcn_rcpf(x); }
__device__ __forceinline__ float fsig(float x) { return frcp(1.f + __expf(-x)); }
} // namespace

// n[c](h,w) = sigmoid(c_map[c][h+DY[c]][w+DX[c]]), zero outside image.
// vote[i] = p[i] * n[7-i].  DX = {1,0,-1,1,-1,1,0,-1}, DY = {1,1,1,0,0,-1,-1,-1}.
// Rolling window: wave walks WALK rows; carries sigma(ch0..2) at h (computed
// one row ahead) and sigma(ch5..7) at h-1 (last row's centers). Each c_map
// element is loaded+sigmoided exactly once (plus 6 boundary dwords/row).
// All loads aligned; all edge handling via selects (no divergent branches).

__global__ __launch_bounds__(256) void bicon_main(
    const float* __restrict__ c_map,
    const int*   __restrict__ target,
    const int*   __restrict__ con_target,
    float* __restrict__ col_i, float* __restrict__ col_j, float* __restrict__ col_x,
    double* __restrict__ bscal)
{
    const int tid  = threadIdx.x;        // 0..255
    const int lane = tid & 63;
    const int wv   = tid >> 6;           // 0..3
    const int half = wv & 1;             // which 256-col half
    const int rg   = wv >> 1;            // row-group within block
    const int b    = blockIdx.y;
    const int hstart = blockIdx.x * ROWSB + rg * WALK;
    const int wq   = half * 256 + lane * 4;   // first of this lane's 4 columns

    const float* cm = c_map      + (size_t)b * CHW;
    const int*   ct = con_target + (size_t)b * CHW;
    const int*   tg = target     + (size_t)b * HW;

    float s_con = 0.f, s_bi = 0.f, s_bce = 0.f, s_dec = 0.f;
    float ci[4] = {0, 0, 0, 0}, cj[4] = {0, 0, 0, 0}, cx[4] = {0, 0, 0, 0};

    auto sig4 = [&](const float4& v, float s[4]) {
        s[0] = fsig(v.x); s[1] = fsig(v.y); s[2] = fsig(v.z); s[3] = fsig(v.w);
    };

    // ---- carried state ----
    float C0[4], C1[4], C2[4];   // sigma(ch0..2) at current row h
    float P5[4], P6[4], P7[4];   // sigma(ch5..7) at row h-1
    {
        const int pb = hstart * Wn + wq;
        sig4(*(const float4*)(cm + 0 * HW + pb), C0);
        sig4(*(const float4*)(cm + 1 * HW + pb), C1);
        sig4(*(const float4*)(cm + 2 * HW + pb), C2);
    }
    if (hstart > 0) {
        const int pb = (hstart - 1) * Wn + wq;
        sig4(*(const float4*)(cm + 5 * HW + pb), P5);
        sig4(*(const float4*)(cm + 6 * HW + pb), P6);
        sig4(*(const float4*)(cm + 7 * HW + pb), P7);
    } else {
#pragma unroll
        for (int k = 0; k < 4; ++k) { P5[k] = 0.f; P6[k] = 0.f; P7[k] = 0.f; }
    }

    const bool edR = (wq + 4 == Wn);     // lane owning the image right edge
    const bool edL = (wq == 0);          // lane owning the image left edge

    int h = hstart;
#pragma unroll 1
    for (int r = 0; r < WALK; ++r, ++h) {
        const int  base  = h * Wn + wq;
        const bool hasDn = (h + 1 < Hn);
        const bool hasUp = (h > 0);

        // ---- independent loads first (MLP): next-row x, boundaries, targets --
        const float4 xf0 = *(const float4*)(cm + 0 * HW + base + Wn);
        const float4 xf1 = *(const float4*)(cm + 1 * HW + base + Wn);
        const float4 xf2 = *(const float4*)(cm + 2 * HW + base + Wn);
        // boundary raw values (all addresses in-bounds by construction;
        // garbage cases masked below)
        const float bx0 = cm[0 * HW + base + Wn + 4];   // ch0 @ (h+1, wq+4)
        const float bx2 = cm[2 * HW + base + Wn - 1];   // ch2 @ (h+1, wq-1)
        const float bx3 = cm[3 * HW + base + 4];        // ch3 @ (h,   wq+4)
        const float bx4 = cm[4 * HW + base - 1];        // ch4 @ (h,   wq-1)
        const float bx5 = cm[5 * HW + base - Wn + 4];   // ch5 @ (h-1, wq+4)
        const float bx7 = cm[7 * HW + base - Wn - 1];   // ch7 @ (h-1, wq-1)
        const int4 t4  = *(const int4*)(tg + base);

        // ---- con_target: 8 channel bits x 4 px -> one uint (byte per px) ----
        unsigned lo = 0u;
#pragma unroll
        for (int c = 0; c < 8; ++c) {
            const int4 u = *(const int4*)(ct + c * HW + base);
            lo |= ((unsigned)u.x << c)        | ((unsigned)u.y << (8 + c)) |
                  ((unsigned)u.z << (16 + c)) | ((unsigned)u.w << (24 + c));
        }

        // ---- conmap for carried centers ch0..2 (select-then-log) ----
#pragma unroll
        for (int k = 0; k < 4; ++k) {
            s_con += fmaxf(__logf(((lo >> (8 * k + 0)) & 1u) ? C0[k] : 1.f - C0[k]), -100.f);
            s_con += fmaxf(__logf(((lo >> (8 * k + 1)) & 1u) ? C1[k] : 1.f - C1[k]), -100.f);
            s_con += fmaxf(__logf(((lo >> (8 * k + 2)) & 1u) ? C2[k] : 1.f - C2[k]), -100.f);
        }

        // ---- centers ch3..7 with fused conmap (logd trick) ----
        float c3[4], c4[4], c5[4], c6[4], c7[4];
        auto sigcon = [&](int c, float s[4]) {
            const float4 v = *(const float4*)(cm + c * HW + base);
            const float xs[4] = {v.x, v.y, v.z, v.w};
#pragma unroll
            for (int k = 0; k < 4; ++k) {
                const float e = __expf(-xs[k]);
                const float d = 1.f + e;
                s[k] = frcp(d);
                const float logd = __logf(d);
                s_con += fmaxf(((lo >> (8 * k + c)) & 1u) ? -logd : (-xs[k] - logd),
                               -100.f);
            }
        };
        sigcon(3, c3); sigcon(4, c4); sigcon(5, c5); sigcon(6, c6); sigcon(7, c7);

        // ---- next-row sigmas (centers of h+1, neighbors for votes 5..7) ----
        float F0[4], F1[4], F2[4];
        sig4(xf0, F0); sig4(xf1, F1); sig4(xf2, F2);

        // boundary sigmas
        const float s0b = fsig(bx0), s2b = fsig(bx2), s3b = fsig(bx3);
        const float s4b = fsig(bx4), s5b = fsig(bx5), s7b = fsig(bx7);

        // ---- neighbor arrays n[c] (masked shifts) ----
        float n0[4], n1[4], n2[4], n3[4], n4[4], n5[4], n6[4], n7[4];
#pragma unroll
        for (int k = 0; k < 3; ++k) {
            n0[k] = F0[k + 1]; n3[k] = c3[k + 1]; n5[k] = P5[k + 1];
            n2[k + 1] = F2[k]; n4[k + 1] = c4[k]; n7[k + 1] = P7[k];
        }
        n0[3] = edR ? 0.f : s0b;  n3[3] = edR ? 0.f : s3b;  n5[3] = edR ? 0.f : s5b;
        n2[0] = edL ? 0.f : s2b;  n4[0] = edL ? 0.f : s4b;  n7[0] = edL ? 0.f : s7b;
#pragma unroll
        for (int k = 0; k < 4; ++k) {
            n1[k] = hasDn ? F1[k] : 0.f;
            n6[k] = hasUp ? P6[k] : 0.f;
            if (!hasDn) { n0[k] = 0.f; n2[k] = 0.f; }
            if (!hasUp) { n5[k] = 0.f; n7[k] = 0.f; }
        }

        // ---- votes: vote[i] = p[i] * n[7-i] ----
        float vmax[4] = {0.f, 0.f, 0.f, 0.f}, vmin[4] = {2.f, 2.f, 2.f, 2.f};
        auto vote = [&](int i, const float p[4], const float n[4]) {
#pragma unroll
            for (int k = 0; k < 4; ++k) {
                const float v = p[k] * n[k];
                vmax[k] = fmaxf(vmax[k], v);
                vmin[k] = fminf(vmin[k], v);
                s_bi += fmaxf(__logf(((lo >> (8 * k + i)) & 1u) ? v : 1.f - v),
                              -100.f);
            }
        };
        vote(0, C0, n7); vote(1, C1, n6); vote(2, C2, n5); vote(3, c3, n4);
        vote(4, c4, n3); vote(5, c5, n2); vote(6, c6, n1); vote(7, c7, n0);

        // ---- per-pixel tail: bce, decouple, dice ----
        const int tk[4] = {t4.x, t4.y, t4.z, t4.w};
#pragma unroll
        for (int k = 0; k < 4; ++k) {
            const float fm = vmax[k];
            s_bce += fmaxf(__logf(tk[k] ? fm : 1.f - fm), -100.f);
            const int sc = __popc((int)((lo >> (8 * k)) & 0xffu));
            s_dec += (sc > 0 && sc < 8)
                         ? fmaxf(__logf(1.f - vmin[k]), -100.f) : 0.f;
            ci[k] += (float)tk[k];
            cj[k] += fm;
            cx[k] += tk[k] ? fm : 0.f;
        }

        // ---- rotate the window ----
#pragma unroll
        for (int k = 0; k < 4; ++k) {
            C0[k] = F0[k]; C1[k] = F1[k]; C2[k] = F2[k];
            P5[k] = c5[k]; P6[k] = c6[k]; P7[k] = c7[k];
        }
    }

    // ---- dice partials -> LDS (combine the two row-group waves per half) ----
    __shared__ float cred[3][4][256];   // 12 KB
#pragma unroll
    for (int k = 0; k < 4; ++k) {
        cred[0][wv][(lane << 2) + k] = ci[k];
        cred[1][wv][(lane << 2) + k] = cj[k];
        cred[2][wv][(lane << 2) + k] = cx[k];
    }

    // ---- scalar sums: wave shuffle reduction ----
#pragma unroll
    for (int off = 32; off > 0; off >>= 1) {
        s_con += __shfl_down(s_con, off);
        s_bi  += __shfl_down(s_bi,  off);
        s_bce += __shfl_down(s_bce, off);
        s_dec += __shfl_down(s_dec, off);
    }
    __shared__ float wred[4][4];
    if (lane == 0) {
        wred[wv][0] = s_con; wred[wv][1] = s_bi;
        wred[wv][2] = s_bce; wred[wv][3] = s_dec;
    }
    __syncthreads();

    // waves {hj, hj+2} hold column half hj
#pragma unroll
    for (int j = tid; j < 512; j += 256) {
        const int hj = j >> 8, cidx = j & 255;
        const float a0 = cred[0][hj][cidx] + cred[0][hj + 2][cidx];
        const float a1 = cred[1][hj][cidx] + cred[1][hj + 2][cidx];
        const float a2 = cred[2][hj][cidx] + cred[2][hj + 2][cidx];
        atomicAdd(&col_i[b * Wn + j], a0);
        atomicAdd(&col_j[b * Wn + j], a1);
        atomicAdd(&col_x[b * Wn + j], a2);
    }
    if (tid < 4) {
        bscal[((size_t)blockIdx.y * GX + blockIdx.x) * 4 + tid] =
            (double)(wred[0][tid] + wred[1][tid] + wred[2][tid] + wred[3][tid]);
    }
}

__global__ __launch_bounds__(256) void bicon_finish(
    const float* __restrict__ col_i,
    const float* __restrict__ col_j,
    const float* __restrict__ col_x,
    const double* __restrict__ bscal,
    float* __restrict__ out)
{
    const int tid = threadIdx.x;
    const int col = blockIdx.x * 256 + tid;      // exactly NCOL threads total

    double part;
    {
        const float fi = col_i[col], fj = col_j[col], fx = col_x[col];
        part = (1.0 - (2.0 * (double)fx + 0.001) /
                      ((double)fi + (double)fj + 0.001)) / 8192.0;
    }
    if (tid < 32) {   // 32 bscal slots per block: 32 blocks * 32 = 1024 = NBLK
        const int s = blockIdx.x * 32 + tid;
        const double c0 = bscal[s * 4 + 0], c1 = bscal[s * 4 + 1];
        const double c2 = bscal[s * 4 + 2], c3 = bscal[s * 4 + 3];
        part += -0.8 * c0 / 33554432.0 - 0.2 * c1 / 33554432.0
                - c2 / 4194304.0 - c3 / 4194304.0;
    }
#pragma unroll
    for (int off = 32; off > 0; off >>= 1) part += __shfl_down(part, off);
    __shared__ double red[4];
    if ((tid & 63) == 0) red[tid >> 6] = part;
    __syncthreads();
    if (tid == 0) atomicAdd(out, (float)(red[0] + red[1] + red[2] + red[3]));
}

extern "C" void kernel_launch(void* const* d_in, const int* in_sizes, int n_in,
                              void* d_out, int out_size, void* d_ws, size_t ws_size,
                              hipStream_t stream) {
    const float* c_map      = (const float*)d_in[0];
    const int*   target     = (const int*)d_in[1];
    const int*   con_target = (const int*)d_in[2];
    float* out = (float*)d_out;

    char* ws = (char*)d_ws;
    float*  col_i = (float*)ws;                               // 8192 floats
    float*  col_j = col_i + NCOL;
    float*  col_x = col_j + NCOL;
    double* bscal = (double*)(ws + 3 * NCOL * sizeof(float)); // 1024*4 doubles

    hipMemsetAsync(d_ws, 0, 3 * NCOL * sizeof(float), stream); // zero col tables
    hipMemsetAsync(d_out, 0, sizeof(float), stream);           // finisher atomics here

    dim3 grid(GX, Bn);       // 64 x 16 = 1024 blocks
    dim3 block(256);
    bicon_main<<<grid, block, 0, stream>>>(c_map, target, con_target,
                                           col_i, col_j, col_x, bscal);
    bicon_finish<<<FBLK, 256, 0, stream>>>(col_i, col_j, col_x, bscal, out);
}

// Round 7
// 303.133 us; speedup vs baseline: 1.1611x; 1.0164x over previous
//
#include <hip/hip_runtime.h>

namespace {
constexpr int Bn = 16, Hn = 512, Wn = 512;
constexpr int HW  = Hn * Wn;        // 262144
constexpr int CHW = 8 * HW;         // 2097152
constexpr int NCOL = Bn * Wn;       // 8192 dice columns
constexpr int WALK = 2;             // rows walked per wave
constexpr int GX   = Hn / (2 * WALK); // 128 (block = 2 rowgroups x WALK rows)
constexpr int NBLK = GX * Bn;       // 2048 blocks
constexpr int FBLK = 32;            // finisher blocks; 32*64 slots == NBLK

constexpr float L2E  = 1.4426950408889634f;   // log2(e)
constexpr float LN2  = 0.6931471805599453f;
constexpr float CLMP = -144.26950408889634f;  // -100 / ln2 (clamp in log2 units)

__device__ __forceinline__ float frcp(float x) { return __builtin_amdgcn_rcpf(x); }
#if __has_builtin(__builtin_amdgcn_exp2f)
__device__ __forceinline__ float fexp2(float x) { return __builtin_amdgcn_exp2f(x); }
#else
__device__ __forceinline__ float fexp2(float x) { return exp2f(x); }
#endif
#if __has_builtin(__builtin_amdgcn_logf)
__device__ __forceinline__ float flog2(float x) { return __builtin_amdgcn_logf(x); }
#else
__device__ __forceinline__ float flog2(float x) { return log2f(x); }
#endif
} // namespace

// n[c](h,w) = sigmoid(c_map[c][h+DY[c]][w+DX[c]]), zero outside image.
// vote[i] = p[i] * n[7-i].  DX = {1,0,-1,1,-1,1,0,-1}, DY = {1,1,1,0,0,-1,-1,-1}.
// All BCE sums accumulated in log2 units via log-of-product fusion:
//   conmap ch3-7: sum_c (bit ? -log2 d : -y - log2 d) = -log2(prod d) - sum_{bit=0} y
//   conmap ch0-2 (carried sigma): log2 of select-product
//   bimap: two products of 4 selected votes; exact zero votes (edge shifts)
//   excluded from the product and charged CLMP each when bit=1.
// One x ln2 conversion at the bscal write restores natural-log units.

__global__ __launch_bounds__(256) void bicon_main(
    const float* __restrict__ c_map,
    const int*   __restrict__ target,
    const int*   __restrict__ con_target,
    float* __restrict__ col_i, float* __restrict__ col_j, float* __restrict__ col_x,
    double* __restrict__ bscal)
{
    const int tid  = threadIdx.x;        // 0..255
    const int lane = tid & 63;
    const int wv   = tid >> 6;           // 0..3
    const int half = wv & 1;             // 256-col half
    const int rg   = wv >> 1;            // row-group within block
    const int b    = blockIdx.y;
    const int hstart = blockIdx.x * (2 * WALK) + rg * WALK;
    const int wq   = half * 256 + lane * 4;   // first of this lane's 4 columns

    const float* cm = c_map      + (size_t)b * CHW;
    const int*   ct = con_target + (size_t)b * CHW;
    const int*   tg = target     + (size_t)b * HW;

    float s_con = 0.f, s_bi = 0.f, s_bce = 0.f, s_dec = 0.f;   // log2 units
    float ci[4] = {0, 0, 0, 0}, cj[4] = {0, 0, 0, 0}, cx[4] = {0, 0, 0, 0};

    auto sig4 = [&](const float4& v, float s[4]) {
        s[0] = frcp(1.f + fexp2(-v.x * L2E));
        s[1] = frcp(1.f + fexp2(-v.y * L2E));
        s[2] = frcp(1.f + fexp2(-v.z * L2E));
        s[3] = frcp(1.f + fexp2(-v.w * L2E));
    };

    // ---- carried window: sigma(ch0..2)@h, sigma(ch5..7)@h-1 ----
    float C0[4], C1[4], C2[4], P5[4], P6[4], P7[4];
    {
        const int pb = hstart * Wn + wq;
        sig4(*(const float4*)(cm + 0 * HW + pb), C0);
        sig4(*(const float4*)(cm + 1 * HW + pb), C1);
        sig4(*(const float4*)(cm + 2 * HW + pb), C2);
    }
    if (hstart > 0) {   // wave-uniform
        const int pb = (hstart - 1) * Wn + wq;
        sig4(*(const float4*)(cm + 5 * HW + pb), P5);
        sig4(*(const float4*)(cm + 6 * HW + pb), P6);
        sig4(*(const float4*)(cm + 7 * HW + pb), P7);
    } else {
#pragma unroll
        for (int k = 0; k < 4; ++k) { P5[k] = 0.f; P6[k] = 0.f; P7[k] = 0.f; }
    }

    const bool edR = (wq + 4 == Wn);
    const bool edL = (wq == 0);

    int h = hstart;
#pragma unroll 1
    for (int r = 0; r < WALK; ++r, ++h) {
        const int  base  = h * Wn + wq;
        const bool hasDn = (h + 1 < Hn);
        const bool hasUp = (h > 0);

        // ---- independent loads first ----
        const float4 xa3 = *(const float4*)(cm + 3 * HW + base);
        const float4 xa4 = *(const float4*)(cm + 4 * HW + base);
        const float4 xa5 = *(const float4*)(cm + 5 * HW + base);
        const float4 xa6 = *(const float4*)(cm + 6 * HW + base);
        const float4 xa7 = *(const float4*)(cm + 7 * HW + base);
        const float4 xf0 = *(const float4*)(cm + 0 * HW + base + Wn);
        const float4 xf1 = *(const float4*)(cm + 1 * HW + base + Wn);
        const float4 xf2 = *(const float4*)(cm + 2 * HW + base + Wn);
        const float bx0 = cm[0 * HW + base + Wn + 4];
        const float bx2 = cm[2 * HW + base + Wn - 1];
        const float bx3 = cm[3 * HW + base + 4];
        const float bx4 = cm[4 * HW + base - 1];
        const float bx5 = cm[5 * HW + base - Wn + 4];
        const float bx7 = cm[7 * HW + base - Wn - 1];
        const int4  t4  = *(const int4*)(tg + base);

        unsigned lo = 0u;
#pragma unroll
        for (int c = 0; c < 8; ++c) {
            const int4 u = *(const int4*)(ct + c * HW + base);
            lo |= ((unsigned)u.x << c)        | ((unsigned)u.y << (8 + c)) |
                  ((unsigned)u.z << (16 + c)) | ((unsigned)u.w << (24 + c));
        }

        // ---- fresh centers ch3-7: sigma + conmap d-product accumulation ----
        float dp[4] = {1.f, 1.f, 1.f, 1.f};   // prod of d over ch3..7
        float ys[4] = {0.f, 0.f, 0.f, 0.f};   // sum of y where bit==0
        float c3[4], c4[4], c5[4], c6[4], c7[4];
        auto fresh = [&](int c, const float4& v, float s[4]) {
            const float xs[4] = {v.x, v.y, v.z, v.w};
#pragma unroll
            for (int k = 0; k < 4; ++k) {
                const float y = xs[k] * L2E;
                const float e = fexp2(-y);
                const float d = 1.f + e;
                s[k] = frcp(d);
                dp[k] *= d;
                ys[k] += ((lo >> (8 * k + c)) & 1u) ? 0.f : y;
            }
        };
        fresh(3, xa3, c3); fresh(4, xa4, c4); fresh(5, xa5, c5);
        fresh(6, xa6, c6); fresh(7, xa7, c7);

        // ---- conmap: carried ch0-2 select-product + ch3-7 d-form (2 logs/px) --
#pragma unroll
        for (int k = 0; k < 4; ++k) {
            const float q0 = ((lo >> (8 * k + 0)) & 1u) ? C0[k] : 1.f - C0[k];
            const float q1 = ((lo >> (8 * k + 1)) & 1u) ? C1[k] : 1.f - C1[k];
            const float q2 = ((lo >> (8 * k + 2)) & 1u) ? C2[k] : 1.f - C2[k];
            s_con += flog2(q0 * q1 * q2) - flog2(dp[k]) - ys[k];
        }

        // ---- next-row sigmas + boundary sigmas ----
        float F0[4], F1[4], F2[4];
        sig4(xf0, F0); sig4(xf1, F1); sig4(xf2, F2);
        const float s0b = frcp(1.f + fexp2(-bx0 * L2E));
        const float s2b = frcp(1.f + fexp2(-bx2 * L2E));
        const float s3b = frcp(1.f + fexp2(-bx3 * L2E));
        const float s4b = frcp(1.f + fexp2(-bx4 * L2E));
        const float s5b = frcp(1.f + fexp2(-bx5 * L2E));
        const float s7b = frcp(1.f + fexp2(-bx7 * L2E));

        // ---- neighbor arrays n[c] (masked shifts) ----
        float n0[4], n1[4], n2[4], n3[4], n4[4], n5[4], n6[4], n7[4];
#pragma unroll
        for (int k = 0; k < 3; ++k) {
            n0[k] = F0[k + 1]; n3[k] = c3[k + 1]; n5[k] = P5[k + 1];
            n2[k + 1] = F2[k]; n4[k + 1] = c4[k]; n7[k + 1] = P7[k];
        }
        n0[3] = edR ? 0.f : s0b;  n3[3] = edR ? 0.f : s3b;  n5[3] = edR ? 0.f : s5b;
        n2[0] = edL ? 0.f : s2b;  n4[0] = edL ? 0.f : s4b;  n7[0] = edL ? 0.f : s7b;
#pragma unroll
        for (int k = 0; k < 4; ++k) {
            n1[k] = hasDn ? F1[k] : 0.f;
            n6[k] = hasUp ? P6[k] : 0.f;
            if (!hasDn) { n0[k] = 0.f; n2[k] = 0.f; }
            if (!hasUp) { n5[k] = 0.f; n7[k] = 0.f; }
        }

        // ---- votes + bimap product accumulation ----
        float vmax[4] = {0.f, 0.f, 0.f, 0.f}, vmin[4] = {2.f, 2.f, 2.f, 2.f};
        float pr[4]   = {1.f, 1.f, 1.f, 1.f};
        float zc[4]   = {0.f, 0.f, 0.f, 0.f};   // count of bit=1 zero-votes
        auto vote = [&](int i, const float p[4], const float n[4]) {
#pragma unroll
            for (int k = 0; k < 4; ++k) {
                const float v = p[k] * n[k];
                vmax[k] = fmaxf(vmax[k], v);
                vmin[k] = fminf(vmin[k], v);
                const bool bit = (lo >> (8 * k + i)) & 1u;
                const bool z   = bit && (v == 0.f);     // only from masked edges
                float sel = bit ? v : 1.f - v;
                sel = z ? 1.f : sel;
                zc[k] += z ? 1.f : 0.f;
                pr[k] *= sel;
            }
        };
        vote(0, C0, n7); vote(1, C1, n6); vote(2, C2, n5); vote(3, c3, n4);
#pragma unroll
        for (int k = 0; k < 4; ++k) { s_bi += flog2(pr[k]); pr[k] = 1.f; }
        vote(4, c4, n3); vote(5, c5, n2); vote(6, c6, n1); vote(7, c7, n0);
#pragma unroll
        for (int k = 0; k < 4; ++k) { s_bi += flog2(pr[k]) + CLMP * zc[k]; }

        // ---- per-pixel tail ----
        const int tk[4] = {t4.x, t4.y, t4.z, t4.w};
#pragma unroll
        for (int k = 0; k < 4; ++k) {
            const float fm = vmax[k];
            s_bce += fmaxf(flog2(tk[k] ? fm : 1.f - fm), CLMP);
            const int sc = __popc((int)((lo >> (8 * k)) & 0xffu));
            s_dec += (sc > 0 && sc < 8) ? fmaxf(flog2(1.f - vmin[k]), CLMP) : 0.f;
            ci[k] += (float)tk[k];
            cj[k] += fm;
            cx[k] += tk[k] ? fm : 0.f;
        }

        // ---- rotate window ----
#pragma unroll
        for (int k = 0; k < 4; ++k) {
            C0[k] = F0[k]; C1[k] = F1[k]; C2[k] = F2[k];
            P5[k] = c5[k]; P6[k] = c6[k]; P7[k] = c7[k];
        }
    }

    // ---- dice partials -> LDS ----
    __shared__ float cred[3][4][256];   // 12 KB
#pragma unroll
    for (int k = 0; k < 4; ++k) {
        cred[0][wv][(lane << 2) + k] = ci[k];
        cred[1][wv][(lane << 2) + k] = cj[k];
        cred[2][wv][(lane << 2) + k] = cx[k];
    }

    // ---- scalar sums: wave shuffle reduction ----
#pragma unroll
    for (int off = 32; off > 0; off >>= 1) {
        s_con += __shfl_down(s_con, off);
        s_bi  += __shfl_down(s_bi,  off);
        s_bce += __shfl_down(s_bce, off);
        s_dec += __shfl_down(s_dec, off);
    }
    __shared__ float wred[4][4];
    if (lane == 0) {   // convert log2 -> ln units here (one mul per sum)
        wred[wv][0] = s_con * LN2; wred[wv][1] = s_bi * LN2;
        wred[wv][2] = s_bce * LN2; wred[wv][3] = s_dec * LN2;
    }
    __syncthreads();

    // waves {hj, hj+2} hold column half hj
#pragma unroll
    for (int j = tid; j < 512; j += 256) {
        const int hj = j >> 8, cidx = j & 255;
        atomicAdd(&col_i[b * Wn + j], cred[0][hj][cidx] + cred[0][hj + 2][cidx]);
        atomicAdd(&col_j[b * Wn + j], cred[1][hj][cidx] + cred[1][hj + 2][cidx]);
        atomicAdd(&col_x[b * Wn + j], cred[2][hj][cidx] + cred[2][hj + 2][cidx]);
    }
    if (tid < 4) {
        bscal[((size_t)blockIdx.y * GX + blockIdx.x) * 4 + tid] =
            (double)(wred[0][tid] + wred[1][tid] + wred[2][tid] + wred[3][tid]);
    }
}

__global__ __launch_bounds__(256) void bicon_finish(
    const float* __restrict__ col_i,
    const float* __restrict__ col_j,
    const float* __restrict__ col_x,
    const double* __restrict__ bscal,
    float* __restrict__ out)
{
    const int tid = threadIdx.x;
    const int col = blockIdx.x * 256 + tid;      // exactly NCOL threads total

    double part;
    {
        const float fi = col_i[col], fj = col_j[col], fx = col_x[col];
        part = (1.0 - (2.0 * (double)fx + 0.001) /
                      ((double)fi + (double)fj + 0.001)) / 8192.0;
    }
    if (tid < 64) {   // 64 bscal slots per block: 32 blocks * 64 = 2048 = NBLK
        const int s = blockIdx.x * 64 + tid;
        const double c0 = bscal[s * 4 + 0], c1 = bscal[s * 4 + 1];
        const double c2 = bscal[s * 4 + 2], c3 = bscal[s * 4 + 3];
        part += -0.8 * c0 / 33554432.0 - 0.2 * c1 / 33554432.0
                - c2 / 4194304.0 - c3 / 4194304.0;
    }
#pragma unroll
    for (int off = 32; off > 0; off >>= 1) part += __shfl_down(part, off);
    __shared__ double red[4];
    if ((tid & 63) == 0) red[tid >> 6] = part;
    __syncthreads();
    if (tid == 0) atomicAdd(out, (float)(red[0] + red[1] + red[2] + red[3]));
}

extern "C" void kernel_launch(void* const* d_in, const int* in_sizes, int n_in,
                              void* d_out, int out_size, void* d_ws, size_t ws_size,
                              hipStream_t stream) {
    const float* c_map      = (const float*)d_in[0];
    const int*   target     = (const int*)d_in[1];
    const int*   con_target = (const int*)d_in[2];
    float* out = (float*)d_out;

    char* ws = (char*)d_ws;
    float*  col_i = (float*)ws;                               // 8192 floats
    float*  col_j = col_i + NCOL;
    float*  col_x = col_j + NCOL;
    double* bscal = (double*)(ws + 3 * NCOL * sizeof(float)); // 2048*4 doubles

    hipMemsetAsync(d_ws, 0, 3 * NCOL * sizeof(float), stream); // zero col tables
    hipMemsetAsync(d_out, 0, sizeof(float), stream);           // finisher atomics here

    dim3 grid(GX, Bn);       // 128 x 16 = 2048 blocks
    dim3 block(256);
    bicon_main<<<grid, block, 0, stream>>>(c_map, target, con_target,
                                           col_i, col_j, col_x, bscal);
    bicon_finish<<<FBLK, 256, 0, stream>>>(col_i, col_j, col_x, bscal, out);
}